// Round 7
// baseline (3397.559 us; speedup 1.0000x reference)
//
#include <hip/hip_runtime.h>

#define BN_EPS 1e-5f
#define NBLK 1024

struct SMem {
  float2 pred[256];
  float2 smr[64];
  float2 smr2[64];
  float  sacc[4][64][4];
  float  saccD[4][64][4];
  float  logits[320];
  float  mnrs[20];
};

// ---------------- device-scope grid barrier (monotonic counter, replay-safe:
// host zeroes the counter each call via hipMemsetAsync before launch)
__device__ __forceinline__ void gsync(unsigned* bar, unsigned target) {
  __syncthreads();                       // drains this block's vmem (compiler emits vmcnt(0))
  if (threadIdx.x == 0) {
    __threadfence();                     // agent-scope release (cross-XCD visibility)
    atomicAdd(bar, 1u);
    while (__hip_atomic_load(bar, __ATOMIC_RELAXED, __HIP_MEMORY_SCOPE_AGENT) < target)
      __builtin_amdgcn_s_sleep(8);
    __threadfence();                     // acquire
  }
  __syncthreads();
}

// ---------------- stats prologue: [C][nPart] partials -> smr[c]=(mean,rstd)
// fixed-order tree, identical in every block (deterministic)
template<int C>
__device__ __forceinline__ void stats_prologue(const float2* __restrict__ part,
                                               int nPart, float invN,
                                               float2* smr, float2* pred) {
  const int TPC = 256 / C;
  int c  = threadIdx.x / TPC;
  int sl = threadIdx.x - c * TPC;
  float s = 0.f, s2 = 0.f;
  for (int j = sl; j < nPart; j += TPC) {
    float2 p = part[c * nPart + j];
    s += p.x; s2 += p.y;
  }
  pred[threadIdx.x] = make_float2(s, s2);
  __syncthreads();
  for (int st = TPC >> 1; st; st >>= 1) {
    if (sl < st) {
      pred[threadIdx.x].x += pred[threadIdx.x + st].x;
      pred[threadIdx.x].y += pred[threadIdx.x + st].y;
    }
    __syncthreads();
  }
  if (sl == 0) {
    float m   = pred[threadIdx.x].x * invN;
    float var = fmaxf(pred[threadIdx.x].y * invN - m * m, 0.f);
    smr[c] = make_float2(m, rsqrtf(var + BN_EPS));
  }
  __syncthreads();
}

// ---------------- adder stage: virtual block = 64 positions x CT out-channels,
// 4 waves = 4 ci-groups (in-block split-K, LDS reduce). Grid-stride over NVB.
// INBN: input raw pre-BN -> relu((v-m)*r) on in-bounds loads only (padding
// stays 0: activation precedes patch extraction). DOWN: fused 1x1 stride-2
// adder via the always-in-bounds center tap.
template<int CIN, int CT, bool INBN, bool DOWN>
__device__ __forceinline__ void adder_stage(SMem& sm,
    const float* __restrict__ xs, const float2* __restrict__ inpart, int nPartIn, float invNIn,
    const float* __restrict__ w, const float* __restrict__ wD,
    float* __restrict__ raw, float2* __restrict__ parts,
    float* __restrict__ rawD, float2* __restrict__ partsD,
    int Cout, int H, int W, int Ho, int Wo, int stride, int pad,
    int posChunks, int NVB) {
  if (INBN) stats_prologue<CIN>(inpart, nPartIn, invNIn, sm.smr, sm.pred);
  const int HWo = Ho * Wo, HW = H * W;
  const int zl = threadIdx.x >> 6, pl = threadIdx.x & 63;
  const int CPZ = CIN / 4;              // ci per wave-group
  for (int vb = blockIdx.x; vb < NVB; vb += NBLK) {
    int cog = vb / posChunks, pc = vb - cog * posChunks;
    int co0 = cog * CT;
    int i = pc * 64 + pl;
    int b = i / HWo, hw = i - b * HWo;
    int ho = hw / Wo, wo = hw - ho * Wo;
    int off[9]; bool val[9];
    #pragma unroll
    for (int kh = 0; kh < 3; kh++) {
      int hh = ho * stride + kh - pad;
      bool hv = (hh >= 0) & (hh < H);
      #pragma unroll
      for (int kw = 0; kw < 3; kw++) {
        int ww = wo * stride + kw - pad;
        val[kh * 3 + kw] = hv & (ww >= 0) & (ww < W);
        off[kh * 3 + kw] = hh * W + ww;
      }
    }
    float acc[CT];
    float accD[DOWN ? CT : 1];
    #pragma unroll
    for (int c = 0; c < CT; c++) acc[c] = 0.f;
    if (DOWN) {
      #pragma unroll
      for (int c = 0; c < CT; c++) accD[c] = 0.f;
    }
    const int ci0 = zl * CPZ;
    #pragma unroll 1
    for (int bb = 0; bb < CPZ; bb += 4) {
      float p[4][9];
      #pragma unroll
      for (int u = 0; u < 4; u++) {
        const float* xp = xs + (b * CIN + ci0 + bb + u) * HW;
        float m = 0.f, r = 0.f;
        if (INBN) { float2 t = sm.smr[ci0 + bb + u]; m = t.x; r = t.y; }
        #pragma unroll
        for (int t9 = 0; t9 < 9; t9++) {
          float v = val[t9] ? xp[off[t9]] : 0.f;
          if (INBN) v = val[t9] ? fmaxf((v - m) * r, 0.f) : 0.f;
          p[u][t9] = v;
        }
      }
      #pragma unroll
      for (int c = 0; c < CT; c++) {
        const float* wp = w + ((co0 + c) * CIN + ci0 + bb) * 9;   // wave-uniform
        #pragma unroll
        for (int u = 0; u < 4; u++)
          #pragma unroll
          for (int t9 = 0; t9 < 9; t9++)
            acc[c] += fabsf(p[u][t9] - wp[u * 9 + t9]);
        if (DOWN) {
          const float* wdp = wD + (co0 + c) * CIN + ci0 + bb;
          #pragma unroll
          for (int u = 0; u < 4; u++) accD[c] += fabsf(p[u][4] - wdp[u]);
        }
      }
    }
    #pragma unroll
    for (int c = 0; c < CT; c++) sm.sacc[zl][pl][c] = acc[c];
    if (DOWN) {
      #pragma unroll
      for (int c = 0; c < CT; c++) sm.saccD[zl][pl][c] = accD[c];
    }
    __syncthreads();
    if (threadIdx.x < 64 * CT) {
      int c = threadIdx.x >> 6;     // wave id = out-channel slot
      float v = -(sm.sacc[0][pl][c] + sm.sacc[1][pl][c] + sm.sacc[2][pl][c] + sm.sacc[3][pl][c]);
      raw[(b * Cout + co0 + c) * HWo + hw] = v;
      float sx = v, sy = v * v;
      #pragma unroll
      for (int o = 32; o; o >>= 1) { sx += __shfl_down(sx, o, 64); sy += __shfl_down(sy, o, 64); }
      if (pl == 0) parts[(co0 + c) * posChunks + pc] = make_float2(sx, sy);
      if (DOWN) {
        float vd = -(sm.saccD[0][pl][c] + sm.saccD[1][pl][c] + sm.saccD[2][pl][c] + sm.saccD[3][pl][c]);
        rawD[(b * Cout + co0 + c) * HWo + hw] = vd;
        float dx = vd, dy = vd * vd;
        #pragma unroll
        for (int o = 32; o; o >>= 1) { dx += __shfl_down(dx, o, 64); dy += __shfl_down(dy, o, 64); }
        if (pl == 0) partsD[(co0 + c) * posChunks + pc] = make_float2(dx, dy);
      }
    }
    __syncthreads();
  }
}

// ---------------- combine: h = relu(bn(raw2) + id). IDM 0: id=idsrc;
// 1: id=bn(idsrc); 2: id=relu(bn(idsrc)). POOL (HW==64): pooled[b*C+c].
template<int IDM, int C, bool POOL>
__device__ __forceinline__ void combine_stage(SMem& sm,
    const float* __restrict__ raw2, const float2* __restrict__ part2,
    const float* __restrict__ idsrc, const float2* __restrict__ partI,
    int nPart, float invN, float* __restrict__ outp, int HW, int NVB) {
  stats_prologue<C>(part2, nPart, invN, sm.smr, sm.pred);
  if (IDM) stats_prologue<C>(partI, nPart, invN, sm.smr2, sm.pred);
  for (int vb = blockIdx.x; vb < NVB; vb += NBLK) {
    int idx = vb * 256 + threadIdx.x;
    int c = (idx / HW) % C;
    float2 t2 = sm.smr[c];
    float y = (raw2[idx] - t2.x) * t2.y;
    float id;
    if (IDM == 0) id = idsrc[idx];
    else {
      float2 tI = sm.smr2[c];
      id = (idsrc[idx] - tI.x) * tI.y;
      if (IDM == 2) id = fmaxf(id, 0.f);
    }
    float h = fmaxf(y + id, 0.f);
    if (!POOL) {
      outp[idx] = h;
    } else {
      float s = h;
      #pragma unroll
      for (int o = 32; o; o >>= 1) s += __shfl_down(s, o, 64);
      if ((threadIdx.x & 63) == 0) outp[idx >> 6] = s * (1.f / 64.f);
    }
  }
}

// ---------------- stem conv + per-wave BN partials (nPart=512)
__device__ __forceinline__ void stem_stage(const float* __restrict__ x,
                                           const float* __restrict__ w,
                                           float* __restrict__ raw,
                                           float2* __restrict__ parts) {
  for (int vb = blockIdx.x; vb < 2048; vb += NBLK) {
    int e = vb * 256 + threadIdx.x;
    int b = e >> 14, co = (e >> 10) & 15, hw = e & 1023;
    int ho = hw >> 5, wo = hw & 31;
    float acc = 0.f;
    #pragma unroll
    for (int ci = 0; ci < 3; ci++) {
      const float* xp = x + (b * 3 + ci) * 1024;
      #pragma unroll
      for (int kh = 0; kh < 3; kh++) {
        int hh = ho + kh - 1;
        bool hv = (hh >= 0) & (hh < 32);
        #pragma unroll
        for (int kw = 0; kw < 3; kw++) {
          int ww = wo + kw - 1;
          float xv = (hv & (ww >= 0) & (ww < 32)) ? xp[hh * 32 + ww] : 0.f;
          acc += xv * w[((co * 3 + ci) * 3 + kh) * 3 + kw];
        }
      }
    }
    raw[e] = acc;
    float sx = acc, sy = acc * acc;
    #pragma unroll
    for (int o = 32; o; o >>= 1) { sx += __shfl_down(sx, o, 64); sy += __shfl_down(sy, o, 64); }
    if ((threadIdx.x & 63) == 0) {
      int q = vb & 3, wid = threadIdx.x >> 6;
      parts[co * 512 + b * 16 + q * 4 + wid] = make_float2(sx, sy);
    }
  }
}

// ---------------- head (block 0 only)
__device__ __forceinline__ void head_stage(SMem& sm, const float* __restrict__ pooled,
                                           const float* __restrict__ fcw,
                                           float* __restrict__ out) {
  if (blockIdx.x != 0) return;
  for (int t = threadIdx.x; t < 320; t += 256) {
    int b = t / 10, o = t - b * 10;
    float s = 0.f;
    #pragma unroll
    for (int c = 0; c < 64; c++) s += pooled[b * 64 + c] * fcw[o * 64 + c];
    sm.logits[t] = s;
  }
  __syncthreads();
  if (threadIdx.x < 10) {
    float s = 0.f;
    for (int b = 0; b < 32; b++) s += sm.logits[b * 10 + threadIdx.x];
    float m = s * (1.f / 32.f);
    float v = 0.f;
    for (int b = 0; b < 32; b++) { float d = sm.logits[b * 10 + threadIdx.x] - m; v += d * d; }
    sm.mnrs[threadIdx.x] = m;
    sm.mnrs[10 + threadIdx.x] = rsqrtf(v * (1.f / 32.f) + BN_EPS);
  }
  __syncthreads();
  for (int t = threadIdx.x; t < 320; t += 256)
    out[t] = (sm.logits[t] - sm.mnrs[t % 10]) * sm.mnrs[10 + t % 10];
}

// ================================================================ meganet
__global__ void __launch_bounds__(256, 4)
meganet(const float* __restrict__ x, const float* __restrict__ conv1w,
        const float* __restrict__ l1w, const float* __restrict__ l2w0,
        const float* __restrict__ l2ws, const float* __restrict__ l2down,
        const float* __restrict__ l3w0, const float* __restrict__ l3ws,
        const float* __restrict__ l3down, const float* __restrict__ fcw,
        float* __restrict__ out, float* __restrict__ base, unsigned* __restrict__ bar) {
  __shared__ SMem sm;
  const int S = 524288;
  float* R0 = base;          float* RA = base + S;
  float* RB = base + 2 * S;  float* RD = base + 3 * S;
  float* H0 = base + 4 * S;  float* H1 = base + 5 * S;
  float* pooled = base + 6 * S;
  float2* partS = (float2*)(pooled + 4096);
  float2* partA = partS + 8192;
  float2* partB = partA + 8192;
  float2* partD = partB + 8192;
  const float INV1 = 1.f / 32768.f, INV2 = 1.f / 8192.f, INV3 = 1.f / 2048.f;
  unsigned seq = 0;
  auto GS = [&]() { gsync(bar, (unsigned)NBLK * ++seq); };

  stem_stage(x, conv1w, R0, partS); GS();

  // ---- layer1: 16ch @32x32. CT=4, posChunks=512, NVB=2048
  adder_stage<16,4,true ,false>(sm, R0, partS, 512, INV1, l1w + 0*2304, nullptr, RA, partA, nullptr, nullptr, 16, 32,32,32,32, 1,1, 512, 2048); GS();
  adder_stage<16,4,true ,false>(sm, RA, partA, 512, INV1, l1w + 1*2304, nullptr, RB, partB, nullptr, nullptr, 16, 32,32,32,32, 1,1, 512, 2048); GS();
  combine_stage<2,16,false>(sm, RB, partB, R0, partS, 512, INV1, H0, 1024, 2048); GS();

  adder_stage<16,4,false,false>(sm, H0, nullptr, 0, 0.f, l1w + 2*2304, nullptr, RA, partA, nullptr, nullptr, 16, 32,32,32,32, 1,1, 512, 2048); GS();
  adder_stage<16,4,true ,false>(sm, RA, partA, 512, INV1, l1w + 3*2304, nullptr, RB, partB, nullptr, nullptr, 16, 32,32,32,32, 1,1, 512, 2048); GS();
  combine_stage<0,16,false>(sm, RB, partB, H0, nullptr, 512, INV1, H1, 1024, 2048); GS();

  adder_stage<16,4,false,false>(sm, H1, nullptr, 0, 0.f, l1w + 4*2304, nullptr, RA, partA, nullptr, nullptr, 16, 32,32,32,32, 1,1, 512, 2048); GS();
  adder_stage<16,4,true ,false>(sm, RA, partA, 512, INV1, l1w + 5*2304, nullptr, RB, partB, nullptr, nullptr, 16, 32,32,32,32, 1,1, 512, 2048); GS();
  combine_stage<0,16,false>(sm, RB, partB, H1, nullptr, 512, INV1, H0, 1024, 2048); GS();

  // ---- layer2: 32ch @16x16. CT=2, posChunks=128, NVB=2048 (combine 1024)
  adder_stage<16,2,false,true >(sm, H0, nullptr, 0, 0.f, l2w0, l2down, RA, partA, RD, partD, 32, 32,32,16,16, 2,1, 128, 2048); GS();
  adder_stage<32,2,true ,false>(sm, RA, partA, 128, INV2, l2ws + 0*9216, nullptr, RB, partB, nullptr, nullptr, 32, 16,16,16,16, 1,1, 128, 2048); GS();
  combine_stage<1,32,false>(sm, RB, partB, RD, partD, 128, INV2, H1, 256, 1024); GS();

  adder_stage<32,2,false,false>(sm, H1, nullptr, 0, 0.f, l2ws + 1*9216, nullptr, RA, partA, nullptr, nullptr, 32, 16,16,16,16, 1,1, 128, 2048); GS();
  adder_stage<32,2,true ,false>(sm, RA, partA, 128, INV2, l2ws + 2*9216, nullptr, RB, partB, nullptr, nullptr, 32, 16,16,16,16, 1,1, 128, 2048); GS();
  combine_stage<0,32,false>(sm, RB, partB, H1, nullptr, 128, INV2, H0, 256, 1024); GS();

  adder_stage<32,2,false,false>(sm, H0, nullptr, 0, 0.f, l2ws + 3*9216, nullptr, RA, partA, nullptr, nullptr, 32, 16,16,16,16, 1,1, 128, 2048); GS();
  adder_stage<32,2,true ,false>(sm, RA, partA, 128, INV2, l2ws + 4*9216, nullptr, RB, partB, nullptr, nullptr, 32, 16,16,16,16, 1,1, 128, 2048); GS();
  combine_stage<0,32,false>(sm, RB, partB, H0, nullptr, 128, INV2, H1, 256, 1024); GS();

  // ---- layer3: 64ch @8x8. CT=2, posChunks=32, NVB=1024 (combine 512)
  adder_stage<32,2,false,true >(sm, H1, nullptr, 0, 0.f, l3w0, l3down, RA, partA, RD, partD, 64, 16,16,8,8, 2,1, 32, 1024); GS();
  adder_stage<64,2,true ,false>(sm, RA, partA, 32, INV3, l3ws + 0*36864, nullptr, RB, partB, nullptr, nullptr, 64, 8,8,8,8, 1,1, 32, 1024); GS();
  combine_stage<1,64,false>(sm, RB, partB, RD, partD, 32, INV3, H0, 64, 512); GS();

  adder_stage<64,2,false,false>(sm, H0, nullptr, 0, 0.f, l3ws + 1*36864, nullptr, RA, partA, nullptr, nullptr, 64, 8,8,8,8, 1,1, 32, 1024); GS();
  adder_stage<64,2,true ,false>(sm, RA, partA, 32, INV3, l3ws + 2*36864, nullptr, RB, partB, nullptr, nullptr, 64, 8,8,8,8, 1,1, 32, 1024); GS();
  combine_stage<0,64,false>(sm, RB, partB, H0, nullptr, 32, INV3, H1, 64, 512); GS();

  adder_stage<64,2,false,false>(sm, H1, nullptr, 0, 0.f, l3ws + 3*36864, nullptr, RA, partA, nullptr, nullptr, 64, 8,8,8,8, 1,1, 32, 1024); GS();
  adder_stage<64,2,true ,false>(sm, RA, partA, 32, INV3, l3ws + 4*36864, nullptr, RB, partB, nullptr, nullptr, 64, 8,8,8,8, 1,1, 32, 1024); GS();
  combine_stage<0,64,true >(sm, RB, partB, H1, nullptr, 32, INV3, pooled, 64, 512); GS();

  head_stage(sm, pooled, fcw, out);
}

// ================================================================ host
extern "C" void kernel_launch(void* const* d_in, const int* in_sizes, int n_in,
                              void* d_out, int out_size, void* d_ws, size_t ws_size,
                              hipStream_t stream) {
  const float* x      = (const float*)d_in[0];
  const float* conv1w = (const float*)d_in[1];
  const float* l1w    = (const float*)d_in[2];
  const float* l2w0   = (const float*)d_in[3];
  const float* l2ws   = (const float*)d_in[4];
  const float* l2down = (const float*)d_in[5];
  const float* l3w0   = (const float*)d_in[6];
  const float* l3ws   = (const float*)d_in[7];
  const float* l3down = (const float*)d_in[8];
  const float* fcw    = (const float*)d_in[9];
  float* out = (float*)d_out;

  float* base = (float*)d_ws;
  // barrier counter lives after all tensor/partial buffers (cacheline isolated)
  unsigned* bar = (unsigned*)(base + 6 * 524288 + 4096 + 4 * 2 * 8192 + 256);

  hipMemsetAsync(bar, 0, 64, stream);
  meganet<<<NBLK, 256, 0, stream>>>(x, conv1w, l1w, l2w0, l2ws, l2down,
                                    l3w0, l3ws, l3down, fcw, out, base, bar);
}

// Round 8
// 776.924 us; speedup vs baseline: 4.3731x; 4.3731x over previous
//
#include <hip/hip_runtime.h>

#define BN_EPS 1e-5f

// ---------------- stats prologue: [C][nPart] (sum,sumsq) -> smr[c]=(rstd, -mean*rstd)
// fixed-order tree, identical in every block (deterministic).
template<int C>
__device__ __forceinline__ void stats_prologue(const float2* __restrict__ part,
                                               int nPart, float invN,
                                               float2* smr, float2* pred) {
  const int TPC = 256 / C;
  int c  = threadIdx.x / TPC;
  int sl = threadIdx.x - c * TPC;
  float s = 0.f, s2 = 0.f;
  for (int j = sl; j < nPart; j += TPC) {
    float2 p = part[c * nPart + j];
    s += p.x; s2 += p.y;
  }
  pred[threadIdx.x] = make_float2(s, s2);
  __syncthreads();
  for (int st = TPC >> 1; st; st >>= 1) {
    if (sl < st) {
      pred[threadIdx.x].x += pred[threadIdx.x + st].x;
      pred[threadIdx.x].y += pred[threadIdx.x + st].y;
    }
    __syncthreads();
  }
  if (sl == 0) {
    float m   = pred[threadIdx.x].x * invN;
    float var = fmaxf(pred[threadIdx.x].y * invN - m * m, 0.f);
    float r   = rsqrtf(var + BN_EPS);
    smr[c] = make_float2(r, -m * r);
  }
  __syncthreads();
}

// ---------------- fused adder
// Virtual input h computed on the fly per tap (INM):
//  0: h = A                                    (materialized)
//  1: h = relu(bnA(A))                          (raw + stats)
//  2: h = relu(bnA(A) + B)                      (fused combine, materialized id)
//  3: h = relu(bnA(A) + bnB(B))                 (fused combine, downsample id)
//  4: h = relu(bnA(A) + relu(bnB(B)))           (fused combine, stem id)
// bn(v) = fmaf(v, r, -m*r). Out-of-bounds taps are 0 (zero-padded patches:
// activation precedes patch extraction) and still hit |0-w| in the adder.
// Block: 256 thr = 4 waves; 64 positions/block, 4 ci-groups (wave = ci-group),
// CT output channels/thread. grid = (posChunks = B*Ho*Wo/64, Cout/CT).
// LDS reduce over ci-groups. Emits per-(block,channel) BN partials.
// DOWN: fused 1x1 stride-2 adder on the same virtual input (center tap).
// HWRITE: co-group 0 writes the (stride-1) center-tap h to hout (materializes
// the identity tensor for the NEXT block's fused combine).
template<int CIN, int CT, int INM, bool DOWN, bool HWRITE>
__global__ void __launch_bounds__(256, 4)
adder_f(const float* __restrict__ A, const float* __restrict__ Bt,
        const float2* __restrict__ pA, int nPA,
        const float2* __restrict__ pB, int nPB, float invNin,
        const float* __restrict__ w, const float* __restrict__ wD,
        float* __restrict__ raw, float2* __restrict__ parts,
        float* __restrict__ rawD, float2* __restrict__ partsD,
        float* __restrict__ hout,
        int Cout, int H, int W, int Ho, int Wo, int stride, int pad,
        int posChunks) {
  __shared__ float2 pred[256];
  __shared__ float2 smA[(INM >= 1) ? CIN : 1];
  __shared__ float2 smB[(INM >= 3) ? CIN : 1];
  __shared__ float  sacc[4][CT][64];
  __shared__ float  saccD[DOWN ? 4 : 1][DOWN ? CT : 1][DOWN ? 64 : 1];
  if (INM >= 1) stats_prologue<CIN>(pA, nPA, invNin, smA, pred);
  if (INM >= 3) stats_prologue<CIN>(pB, nPB, invNin, smB, pred);

  const int HW = H * W, HWo = Ho * Wo;
  const int zl = threadIdx.x >> 6, pl = threadIdx.x & 63;
  const int pc = blockIdx.x, cog = blockIdx.y, co0 = cog * CT;
  const int i  = pc * 64 + pl;
  const int b  = i / HWo, hw = i - b * HWo;
  const int ho = hw / Wo, wo = hw - ho * Wo;

  int off[9]; bool val[9];
  #pragma unroll
  for (int kh = 0; kh < 3; kh++) {
    int hh = ho * stride + kh - pad;
    bool hv = (hh >= 0) & (hh < H);
    #pragma unroll
    for (int kw = 0; kw < 3; kw++) {
      int ww = wo * stride + kw - pad;
      val[kh * 3 + kw] = hv & (ww >= 0) & (ww < W);
      off[kh * 3 + kw] = hh * W + ww;
    }
  }

  float acc[CT];
  float accD[DOWN ? CT : 1];
  #pragma unroll
  for (int c = 0; c < CT; c++) acc[c] = 0.f;
  if (DOWN) {
    #pragma unroll
    for (int c = 0; c < CT; c++) accD[c] = 0.f;
  }

  const int CPZ = CIN / 4;
  const int ci0 = zl * CPZ;
  #pragma unroll 1
  for (int bb = 0; bb < CPZ; bb += 4) {
    float p[4][9];
    #pragma unroll
    for (int u = 0; u < 4; u++) {
      const int ci = ci0 + bb + u;
      const float* Ap = A + (b * CIN + ci) * HW;
      const float* Bp = (INM >= 2) ? (Bt + (b * CIN + ci) * HW) : nullptr;
      float2 tA = make_float2(0.f, 0.f), tB = make_float2(0.f, 0.f);
      if (INM >= 1) tA = smA[ci];
      if (INM >= 3) tB = smB[ci];
      #pragma unroll
      for (int t = 0; t < 9; t++) {
        float v = 0.f;
        if (val[t]) {
          float a = Ap[off[t]];
          if (INM == 0) v = a;
          if (INM == 1) v = fmaxf(fmaf(a, tA.x, tA.y), 0.f);
          if (INM == 2) v = fmaxf(fmaf(a, tA.x, tA.y) + Bp[off[t]], 0.f);
          if (INM == 3) v = fmaxf(fmaf(a, tA.x, tA.y) + fmaf(Bp[off[t]], tB.x, tB.y), 0.f);
          if (INM == 4) v = fmaxf(fmaf(a, tA.x, tA.y) + fmaxf(fmaf(Bp[off[t]], tB.x, tB.y), 0.f), 0.f);
        }
        p[u][t] = v;
      }
      if (HWRITE) {
        if (cog == 0) hout[(b * CIN + ci) * HW + ho * W + wo] = p[u][4];
      }
    }
    #pragma unroll
    for (int c = 0; c < CT; c++) {
      const float* wp = w + ((co0 + c) * CIN + ci0 + bb) * 9;   // wave-uniform -> s_load
      #pragma unroll
      for (int u = 0; u < 4; u++)
        #pragma unroll
        for (int t = 0; t < 9; t++)
          acc[c] += fabsf(p[u][t] - wp[u * 9 + t]);
      if (DOWN) {
        const float* wdp = wD + (co0 + c) * CIN + ci0 + bb;
        #pragma unroll
        for (int u = 0; u < 4; u++) accD[c] += fabsf(p[u][4] - wdp[u]);
      }
    }
  }

  #pragma unroll
  for (int c = 0; c < CT; c++) sacc[zl][c][pl] = acc[c];
  if (DOWN) {
    #pragma unroll
    for (int c = 0; c < CT; c++) saccD[zl][c][pl] = accD[c];
  }
  __syncthreads();

  if (zl < CT) {
    const int c = zl;
    float v = -(sacc[0][c][pl] + sacc[1][c][pl] + sacc[2][c][pl] + sacc[3][c][pl]);
    raw[(b * Cout + co0 + c) * HWo + hw] = v;
    float sx = v, sy = v * v;
    #pragma unroll
    for (int o = 32; o; o >>= 1) { sx += __shfl_down(sx, o, 64); sy += __shfl_down(sy, o, 64); }
    if (pl == 0) parts[(co0 + c) * posChunks + pc] = make_float2(sx, sy);
    if (DOWN) {
      float vd = -(saccD[0][c][pl] + saccD[1][c][pl] + saccD[2][c][pl] + saccD[3][c][pl]);
      rawD[(b * Cout + co0 + c) * HWo + hw] = vd;
      float dx = vd, dy = vd * vd;
      #pragma unroll
      for (int o = 32; o; o >>= 1) { dx += __shfl_down(dx, o, 64); dy += __shfl_down(dy, o, 64); }
      if (pl == 0) partsD[(co0 + c) * posChunks + pc] = make_float2(dx, dy);
    }
  }
}

// ---------------- conv stem + per-block BN partials (nPart=128)
__global__ void __launch_bounds__(256)
conv_stem_bn(const float* __restrict__ x, const float* __restrict__ w,
             float* __restrict__ raw, float2* __restrict__ partials) {
  const int co = blockIdx.y;
  const int i = blockIdx.x * 256 + threadIdx.x;   // over B*1024
  const int b = i >> 10, hw = i & 1023;
  const int ho = hw >> 5, wo = hw & 31;
  float acc = 0.f;
  #pragma unroll
  for (int ci = 0; ci < 3; ci++) {
    const float* xp = x + (b * 3 + ci) * 1024;
    #pragma unroll
    for (int kh = 0; kh < 3; kh++) {
      int hh = ho + kh - 1;
      bool hv = (hh >= 0) & (hh < 32);
      #pragma unroll
      for (int kw = 0; kw < 3; kw++) {
        int ww = wo + kw - 1;
        float xv = (hv & (ww >= 0) & (ww < 32)) ? xp[hh * 32 + ww] : 0.f;
        acc += xv * w[((co * 3 + ci) * 3 + kh) * 3 + kw];
      }
    }
  }
  raw[(b * 16 + co) * 1024 + hw] = acc;

  float sx = acc, sy = acc * acc;
  #pragma unroll
  for (int o = 32; o; o >>= 1) { sx += __shfl_down(sx, o, 64); sy += __shfl_down(sy, o, 64); }
  __shared__ float2 red[4];
  int lane = threadIdx.x & 63, wid = threadIdx.x >> 6;
  if (lane == 0) red[wid] = make_float2(sx, sy);
  __syncthreads();
  if (threadIdx.x == 0) {
    float2 t = red[0];
    t.x += red[1].x + red[2].x + red[3].x;
    t.y += red[1].y + red[2].y + red[3].y;
    partials[co * 128 + blockIdx.x] = t;
  }
}

// ---------------- final combine + global-avg-pool (HW==64)
__global__ void __launch_bounds__(256)
combine_pool(const float* __restrict__ raw2, const float2* __restrict__ part2, int nPart,
             const float* __restrict__ idsrc, float invN, float* __restrict__ pooled) {
  __shared__ float2 s2[64];
  __shared__ float2 pred[256];
  stats_prologue<64>(part2, nPart, invN, s2, pred);
  int idx = blockIdx.x * 256 + threadIdx.x;
  int c = (idx >> 6) & 63;
  float2 t2 = s2[c];
  float h = fmaxf(fmaf(raw2[idx], t2.x, t2.y) + idsrc[idx], 0.f);
  #pragma unroll
  for (int o = 32; o; o >>= 1) h += __shfl_down(h, o, 64);
  if ((threadIdx.x & 63) == 0) pooled[idx >> 6] = h * (1.f / 64.f);
}

// ---------------- head
__global__ void head_k(const float* __restrict__ pooled, const float* __restrict__ fcw,
                       float* __restrict__ out) {
  __shared__ float logits[320];
  __shared__ float mn[10], rs[10];
  int t = threadIdx.x;
  if (t < 320) {
    int b = t / 10, o = t - b * 10;
    float s = 0.f;
    #pragma unroll
    for (int c = 0; c < 64; c++) s += pooled[b * 64 + c] * fcw[o * 64 + c];
    logits[t] = s;
  }
  __syncthreads();
  if (t < 10) {
    float s = 0.f;
    for (int b = 0; b < 32; b++) s += logits[b * 10 + t];
    float m = s * (1.f / 32.f);
    float v = 0.f;
    for (int b = 0; b < 32; b++) { float d = logits[b * 10 + t] - m; v += d * d; }
    mn[t] = m;
    rs[t] = rsqrtf(v * (1.f / 32.f) + BN_EPS);
  }
  __syncthreads();
  if (t < 320) out[t] = (logits[t] - mn[t % 10]) * rs[t % 10];
}

// ================================================================ host
extern "C" void kernel_launch(void* const* d_in, const int* in_sizes, int n_in,
                              void* d_out, int out_size, void* d_ws, size_t ws_size,
                              hipStream_t stream) {
  const float* x      = (const float*)d_in[0];
  const float* conv1w = (const float*)d_in[1];
  const float* l1w    = (const float*)d_in[2];
  const float* l2w0   = (const float*)d_in[3];
  const float* l2ws   = (const float*)d_in[4];
  const float* l2down = (const float*)d_in[5];
  const float* l3w0   = (const float*)d_in[6];
  const float* l3ws   = (const float*)d_in[7];
  const float* l3down = (const float*)d_in[8];
  const float* fcw    = (const float*)d_in[9];
  float* out = (float*)d_out;

  const int S = 524288;                    // 2 MB in floats
  float* base = (float*)d_ws;
  float* R0  = base + 0 * S;               // stem raw
  float* RA  = base + 1 * S;               // a1 raw (per block, transient)
  float* RB0 = base + 2 * S;               // a2 raw double-buffer
  float* RB1 = base + 3 * S;
  float* HA  = base + 4 * S;               // materialized h double-buffer
  float* HB  = base + 5 * S;
  float* RD  = base + 6 * S;               // downsample raw
  float* pooled = base + 7 * S;            // 2048 floats
  float2* partS  = (float2*)(pooled + 4096);
  float2* partA  = partS  + 8192;
  float2* partB0 = partA  + 8192;
  float2* partB1 = partB0 + 8192;
  float2* partD  = partB1 + 8192;

  const float inv1 = 1.f / 32768.f;        // B*32*32
  const float inv2 = 1.f / 8192.f;         // B*16*16
  const float inv3 = 1.f / 2048.f;         // B*8*8

  // 1. stem
  conv_stem_bn<<<dim3(128, 16), 256, 0, stream>>>(x, conv1w, R0, partS);

  // ---- layer1 (16ch @32x32, posChunks=512, CT=4, grid 512x4=2048)
  const dim3 g1(512, 4);
  // 2. a1 L1b0: input = relu(bn(stem))
  adder_f<16,4,1,false,false><<<g1,256,0,stream>>>(R0, nullptr, partS, 128, nullptr, 0, inv1,
      l1w + 0*2304, nullptr, RA, partA, nullptr, nullptr, nullptr, 16, 32,32,32,32, 1,1, 512);
  // 3. a2 L1b0
  adder_f<16,4,1,false,false><<<g1,256,0,stream>>>(RA, nullptr, partA, 512, nullptr, 0, inv1,
      l1w + 1*2304, nullptr, RB0, partB0, nullptr, nullptr, nullptr, 16, 32,32,32,32, 1,1, 512);
  // 4. a1 L1b1: input h0 = relu(bn(RB0) + relu(bn(R0))); writes HA=h0
  adder_f<16,4,4,false,true ><<<g1,256,0,stream>>>(RB0, R0, partB0, 512, partS, 128, inv1,
      l1w + 2*2304, nullptr, RA, partA, nullptr, nullptr, HA, 16, 32,32,32,32, 1,1, 512);
  // 5. a2 L1b1
  adder_f<16,4,1,false,false><<<g1,256,0,stream>>>(RA, nullptr, partA, 512, nullptr, 0, inv1,
      l1w + 3*2304, nullptr, RB1, partB1, nullptr, nullptr, nullptr, 16, 32,32,32,32, 1,1, 512);
  // 6. a1 L1b2: input h1 = relu(bn(RB1) + HA); writes HB=h1
  adder_f<16,4,2,false,true ><<<g1,256,0,stream>>>(RB1, HA, partB1, 512, nullptr, 0, inv1,
      l1w + 4*2304, nullptr, RA, partA, nullptr, nullptr, HB, 16, 32,32,32,32, 1,1, 512);
  // 7. a2 L1b2
  adder_f<16,4,1,false,false><<<g1,256,0,stream>>>(RA, nullptr, partA, 512, nullptr, 0, inv1,
      l1w + 5*2304, nullptr, RB0, partB0, nullptr, nullptr, nullptr, 16, 32,32,32,32, 1,1, 512);

  // ---- layer2 (32ch @16x16, posChunks=128, CT=4, grid 128x8=1024)
  const dim3 g2(128, 8);
  // 8. a1 L2b0 (stride2) + fused 1x1 down: input h2 = relu(bn(RB0) + HB)
  adder_f<16,4,2,true ,false><<<g2,256,0,stream>>>(RB0, HB, partB0, 512, nullptr, 0, inv1,
      l2w0, l2down, RA, partA, RD, partD, nullptr, 32, 32,32,16,16, 2,1, 128);
  // 9. a2 L2b0
  adder_f<32,4,1,false,false><<<g2,256,0,stream>>>(RA, nullptr, partA, 128, nullptr, 0, inv2,
      l2ws + 0*9216, nullptr, RB1, partB1, nullptr, nullptr, nullptr, 32, 16,16,16,16, 1,1, 128);
  // 10. a1 L2b1: input h = relu(bn(RB1) + bn(RD)); writes HA
  adder_f<32,4,3,false,true ><<<g2,256,0,stream>>>(RB1, RD, partB1, 128, partD, 128, inv2,
      l2ws + 1*9216, nullptr, RA, partA, nullptr, nullptr, HA, 32, 16,16,16,16, 1,1, 128);
  // 11. a2 L2b1
  adder_f<32,4,1,false,false><<<g2,256,0,stream>>>(RA, nullptr, partA, 128, nullptr, 0, inv2,
      l2ws + 2*9216, nullptr, RB0, partB0, nullptr, nullptr, nullptr, 32, 16,16,16,16, 1,1, 128);
  // 12. a1 L2b2: input h = relu(bn(RB0) + HA); writes HB
  adder_f<32,4,2,false,true ><<<g2,256,0,stream>>>(RB0, HA, partB0, 128, nullptr, 0, inv2,
      l2ws + 3*9216, nullptr, RA, partA, nullptr, nullptr, HB, 32, 16,16,16,16, 1,1, 128);
  // 13. a2 L2b2
  adder_f<32,4,1,false,false><<<g2,256,0,stream>>>(RA, nullptr, partA, 128, nullptr, 0, inv2,
      l2ws + 4*9216, nullptr, RB1, partB1, nullptr, nullptr, nullptr, 32, 16,16,16,16, 1,1, 128);

  // ---- layer3 (64ch @8x8, posChunks=32, CT=2, grid 32x32=1024)
  const dim3 g3(32, 32);
  // 14. a1 L3b0 (stride2) + fused down: input h = relu(bn(RB1) + HB)
  adder_f<32,2,2,true ,false><<<g3,256,0,stream>>>(RB1, HB, partB1, 128, nullptr, 0, inv2,
      l3w0, l3down, RA, partA, RD, partD, nullptr, 64, 16,16,8,8, 2,1, 32);
  // 15. a2 L3b0
  adder_f<64,2,1,false,false><<<g3,256,0,stream>>>(RA, nullptr, partA, 32, nullptr, 0, inv3,
      l3ws + 0*36864, nullptr, RB0, partB0, nullptr, nullptr, nullptr, 64, 8,8,8,8, 1,1, 32);
  // 16. a1 L3b1: input h = relu(bn(RB0) + bn(RD)); writes HA
  adder_f<64,2,3,false,true ><<<g3,256,0,stream>>>(RB0, RD, partB0, 32, partD, 32, inv3,
      l3ws + 1*36864, nullptr, RA, partA, nullptr, nullptr, HA, 64, 8,8,8,8, 1,1, 32);
  // 17. a2 L3b1
  adder_f<64,2,1,false,false><<<g3,256,0,stream>>>(RA, nullptr, partA, 32, nullptr, 0, inv3,
      l3ws + 2*36864, nullptr, RB1, partB1, nullptr, nullptr, nullptr, 64, 8,8,8,8, 1,1, 32);
  // 18. a1 L3b2: input h = relu(bn(RB1) + HA); writes HB
  adder_f<64,2,2,false,true ><<<g3,256,0,stream>>>(RB1, HA, partB1, 32, nullptr, 0, inv3,
      l3ws + 3*36864, nullptr, RA, partA, nullptr, nullptr, HB, 64, 8,8,8,8, 1,1, 32);
  // 19. a2 L3b2
  adder_f<64,2,1,false,false><<<g3,256,0,stream>>>(RA, nullptr, partA, 32, nullptr, 0, inv3,
      l3ws + 4*36864, nullptr, RB0, partB0, nullptr, nullptr, nullptr, 64, 8,8,8,8, 1,1, 32);

  // 20. final combine + pool: h = relu(bn(RB0) + HB) -> pooled
  combine_pool<<<512, 256, 0, stream>>>(RB0, partB0, 32, HB, inv3, pooled);

  // 21. head
  head_k<<<1, 320, 0, stream>>>(pooled, fcw, out);
}

// Round 9
// 682.929 us; speedup vs baseline: 4.9750x; 1.1376x over previous
//
#include <hip/hip_runtime.h>

#define BN_EPS 1e-5f

// ---------------- stats prologue: [C][nPart] (sum,sumsq) -> smr[c]=(rstd, -mean*rstd)
// fixed-order tree, identical in every block (deterministic).
template<int C>
__device__ __forceinline__ void stats_prologue(const float2* __restrict__ part,
                                               int nPart, float invN,
                                               float2* smr, float2* pred) {
  const int TPC = 256 / C;
  int c  = threadIdx.x / TPC;
  int sl = threadIdx.x - c * TPC;
  float s = 0.f, s2 = 0.f;
  for (int j = sl; j < nPart; j += TPC) {
    float2 p = part[c * nPart + j];
    s += p.x; s2 += p.y;
  }
  pred[threadIdx.x] = make_float2(s, s2);
  __syncthreads();
  for (int st = TPC >> 1; st; st >>= 1) {
    if (sl < st) {
      pred[threadIdx.x].x += pred[threadIdx.x + st].x;
      pred[threadIdx.x].y += pred[threadIdx.x + st].y;
    }
    __syncthreads();
  }
  if (sl == 0) {
    float m   = pred[threadIdx.x].x * invN;
    float var = fmaxf(pred[threadIdx.x].y * invN - m * m, 0.f);
    float r   = rsqrtf(var + BN_EPS);
    smr[c] = make_float2(r, -m * r);
  }
  __syncthreads();
}

// Virtual-input modes (h computed on the fly per tap):
//  0: h = A; 1: h = relu(bnA(A)); 2: h = relu(bnA(A) + B);
//  3: h = relu(bnA(A) + bnB(B)); 4: h = relu(bnA(A) + relu(bnB(B)))
// bn(v) = fmaf(v, r, -m*r). OOB taps are 0 (zero-padded patches; activation
// precedes patch extraction) and still contribute |0 - w|.
template<int INM>
__device__ __forceinline__ float tap_h(bool ok, const float* Ap, const float* Bp,
                                       int off, float2 tA, float2 tB) {
  if (!ok) return 0.f;
  float a = Ap[off];
  if (INM == 0) return a;
  if (INM == 1) return fmaxf(fmaf(a, tA.x, tA.y), 0.f);
  if (INM == 2) return fmaxf(fmaf(a, tA.x, tA.y) + Bp[off], 0.f);
  if (INM == 3) return fmaxf(fmaf(a, tA.x, tA.y) + fmaf(Bp[off], tB.x, tB.y), 0.f);
  /* INM == 4 */ return fmaxf(fmaf(a, tA.x, tA.y) + fmaxf(fmaf(Bp[off], tB.x, tB.y), 0.f), 0.f);
}

// ---------------- big adder: 256 positions/block (4 waves), full Cin/thread,
// CT out-channels/thread. 1D grid = nx*(Cout/CT), XCD-swizzled so each XCD
// owns a contiguous pc-span for ALL co-groups (L2-resident input reuse).
// Emits per-(block,channel) BN partials at parts[co*nx + pc].
// DOWN: fused 1x1 stride-2 adder via the always-valid center tap.
// HWRITE (stride-1 only): co-group 0 writes h (center tap) to hout.
template<int CIN, int CT, int INM, bool DOWN, bool HWRITE>
__global__ void __launch_bounds__(256, 4)
adder_big(const float* __restrict__ A, const float* __restrict__ Bt,
          const float2* __restrict__ pA, int nPA,
          const float2* __restrict__ pB, int nPB, float invNin,
          const float* __restrict__ w, const float* __restrict__ wD,
          float* __restrict__ raw, float2* __restrict__ parts,
          float* __restrict__ rawD, float2* __restrict__ partsD,
          float* __restrict__ hout,
          int Cout, int H, int W, int Ho, int Wo, int stride, int pad, int nx) {
  __shared__ float2 pred[256];
  __shared__ float2 smA[(INM >= 1) ? CIN : 1];
  __shared__ float2 smB[(INM >= 3) ? CIN : 1];
  __shared__ float2 bred[4][CT];
  __shared__ float2 bredD[DOWN ? 4 : 1][DOWN ? CT : 1];
  if (INM >= 1) stats_prologue<CIN>(pA, nPA, invNin, smA, pred);
  if (INM >= 3) stats_prologue<CIN>(pB, nPB, invNin, smB, pred);

  // XCD swizzle: xcd = id&7 owns pc in [xcd*span, (xcd+1)*span) for all cogs
  const int id = blockIdx.x, span = nx >> 3;
  const int xcd = id & 7, slot = id >> 3;
  const int pc  = xcd * span + slot % span;
  const int cog = slot / span, co0 = cog * CT;

  const int HW = H * W, HWo = Ho * Wo;
  const int i  = pc * 256 + threadIdx.x;
  const int b  = i / HWo, hw = i - b * HWo;
  const int ho = hw / Wo, wo = hw - ho * Wo;

  int off[9]; bool val[9];
  #pragma unroll
  for (int kh = 0; kh < 3; kh++) {
    int hh = ho * stride + kh - pad;
    bool hv = (hh >= 0) & (hh < H);
    #pragma unroll
    for (int kw = 0; kw < 3; kw++) {
      int ww = wo * stride + kw - pad;
      val[kh * 3 + kw] = hv & (ww >= 0) & (ww < W);
      off[kh * 3 + kw] = hh * W + ww;
    }
  }

  float acc[CT];
  float accD[DOWN ? CT : 1];
  #pragma unroll
  for (int c = 0; c < CT; c++) acc[c] = 0.f;
  if (DOWN) {
    #pragma unroll
    for (int c = 0; c < CT; c++) accD[c] = 0.f;
  }

  #pragma unroll 1
  for (int cb = 0; cb < CIN; cb += 4) {
    float p[4][9];
    #pragma unroll
    for (int u = 0; u < 4; u++) {
      const int ci = cb + u;
      const float* Ap = A + (b * CIN + ci) * HW;
      const float* Bp = (INM >= 2) ? (Bt + (b * CIN + ci) * HW) : nullptr;
      float2 tA = make_float2(0.f, 0.f), tB = make_float2(0.f, 0.f);
      if (INM >= 1) tA = smA[ci];
      if (INM >= 3) tB = smB[ci];
      #pragma unroll
      for (int t = 0; t < 9; t++) p[u][t] = tap_h<INM>(val[t], Ap, Bp, off[t], tA, tB);
      if (HWRITE) {
        if (cog == 0) hout[(b * CIN + ci) * HW + ho * W + wo] = p[u][4];
      }
    }
    #pragma unroll
    for (int c = 0; c < CT; c++) {
      const float* wp = w + ((co0 + c) * CIN + cb) * 9;   // wave-uniform -> s_load
      #pragma unroll
      for (int u = 0; u < 4; u++)
        #pragma unroll
        for (int t = 0; t < 9; t++)
          acc[c] += fabsf(p[u][t] - wp[u * 9 + t]);
      if (DOWN) {
        const float* wdp = wD + (co0 + c) * CIN + cb;
        #pragma unroll
        for (int u = 0; u < 4; u++) accD[c] += fabsf(p[u][4] - wdp[u]);
      }
    }
  }

  const int lane = threadIdx.x & 63, wid = threadIdx.x >> 6;
  #pragma unroll
  for (int c = 0; c < CT; c++) {
    float v = -acc[c];
    raw[(b * Cout + co0 + c) * HWo + hw] = v;
    float sx = v, sy = v * v;
    #pragma unroll
    for (int o = 32; o; o >>= 1) { sx += __shfl_down(sx, o, 64); sy += __shfl_down(sy, o, 64); }
    if (lane == 0) bred[wid][c] = make_float2(sx, sy);
    if (DOWN) {
      float vd = -accD[c];
      rawD[(b * Cout + co0 + c) * HWo + hw] = vd;
      float dx = vd, dy = vd * vd;
      #pragma unroll
      for (int o = 32; o; o >>= 1) { dx += __shfl_down(dx, o, 64); dy += __shfl_down(dy, o, 64); }
      if (lane == 0) bredD[wid][c] = make_float2(dx, dy);
    }
  }
  __syncthreads();
  if (threadIdx.x < CT) {
    const int c = threadIdx.x;
    float2 t = bred[0][c];
    #pragma unroll
    for (int wv = 1; wv < 4; wv++) { t.x += bred[wv][c].x; t.y += bred[wv][c].y; }
    parts[(co0 + c) * nx + pc] = t;
    if (DOWN) {
      float2 td = bredD[0][c];
      #pragma unroll
      for (int wv = 1; wv < 4; wv++) { td.x += bredD[wv][c].x; td.y += bredD[wv][c].y; }
      partsD[(co0 + c) * nx + pc] = td;
    }
  }
}

// ---------------- small adder (layer3): 64 positions/block, 4 waves = 4
// ci-groups (in-block split-K, LDS reduce), CT out-channels/thread.
// Same 1D XCD-swizzled grid and partial emission as adder_big.
template<int CIN, int CT, int INM, bool DOWN, bool HWRITE>
__global__ void __launch_bounds__(256, 4)
adder_small(const float* __restrict__ A, const float* __restrict__ Bt,
            const float2* __restrict__ pA, int nPA,
            const float2* __restrict__ pB, int nPB, float invNin,
            const float* __restrict__ w, const float* __restrict__ wD,
            float* __restrict__ raw, float2* __restrict__ parts,
            float* __restrict__ rawD, float2* __restrict__ partsD,
            float* __restrict__ hout,
            int Cout, int H, int W, int Ho, int Wo, int stride, int pad, int nx) {
  __shared__ float2 pred[256];
  __shared__ float2 smA[(INM >= 1) ? CIN : 1];
  __shared__ float2 smB[(INM >= 3) ? CIN : 1];
  __shared__ float  sacc[4][CT][64];
  __shared__ float  saccD[DOWN ? 4 : 1][DOWN ? CT : 1][DOWN ? 64 : 1];
  if (INM >= 1) stats_prologue<CIN>(pA, nPA, invNin, smA, pred);
  if (INM >= 3) stats_prologue<CIN>(pB, nPB, invNin, smB, pred);

  const int id = blockIdx.x, span = nx >> 3;
  const int xcd = id & 7, slot = id >> 3;
  const int pc  = xcd * span + slot % span;
  const int cog = slot / span, co0 = cog * CT;

  const int HW = H * W, HWo = Ho * Wo;
  const int zl = threadIdx.x >> 6, pl = threadIdx.x & 63;
  const int i  = pc * 64 + pl;
  const int b  = i / HWo, hw = i - b * HWo;
  const int ho = hw / Wo, wo = hw - ho * Wo;

  int off[9]; bool val[9];
  #pragma unroll
  for (int kh = 0; kh < 3; kh++) {
    int hh = ho * stride + kh - pad;
    bool hv = (hh >= 0) & (hh < H);
    #pragma unroll
    for (int kw = 0; kw < 3; kw++) {
      int ww = wo * stride + kw - pad;
      val[kh * 3 + kw] = hv & (ww >= 0) & (ww < W);
      off[kh * 3 + kw] = hh * W + ww;
    }
  }

  float acc[CT];
  float accD[DOWN ? CT : 1];
  #pragma unroll
  for (int c = 0; c < CT; c++) acc[c] = 0.f;
  if (DOWN) {
    #pragma unroll
    for (int c = 0; c < CT; c++) accD[c] = 0.f;
  }

  const int CPZ = CIN / 4, ci0 = zl * CPZ;
  #pragma unroll 1
  for (int bb = 0; bb < CPZ; bb += 4) {
    float p[4][9];
    #pragma unroll
    for (int u = 0; u < 4; u++) {
      const int ci = ci0 + bb + u;
      const float* Ap = A + (b * CIN + ci) * HW;
      const float* Bp = (INM >= 2) ? (Bt + (b * CIN + ci) * HW) : nullptr;
      float2 tA = make_float2(0.f, 0.f), tB = make_float2(0.f, 0.f);
      if (INM >= 1) tA = smA[ci];
      if (INM >= 3) tB = smB[ci];
      #pragma unroll
      for (int t = 0; t < 9; t++) p[u][t] = tap_h<INM>(val[t], Ap, Bp, off[t], tA, tB);
      if (HWRITE) {
        if (cog == 0) hout[(b * CIN + ci) * HW + ho * W + wo] = p[u][4];
      }
    }
    #pragma unroll
    for (int c = 0; c < CT; c++) {
      const float* wp = w + ((co0 + c) * CIN + ci0 + bb) * 9;
      #pragma unroll
      for (int u = 0; u < 4; u++)
        #pragma unroll
        for (int t = 0; t < 9; t++)
          acc[c] += fabsf(p[u][t] - wp[u * 9 + t]);
      if (DOWN) {
        const float* wdp = wD + (co0 + c) * CIN + ci0 + bb;
        #pragma unroll
        for (int u = 0; u < 4; u++) accD[c] += fabsf(p[u][4] - wdp[u]);
      }
    }
  }

  #pragma unroll
  for (int c = 0; c < CT; c++) sacc[zl][c][pl] = acc[c];
  if (DOWN) {
    #pragma unroll
    for (int c = 0; c < CT; c++) saccD[zl][c][pl] = accD[c];
  }
  __syncthreads();
  if (zl < CT) {
    const int c = zl;
    float v = -(sacc[0][c][pl] + sacc[1][c][pl] + sacc[2][c][pl] + sacc[3][c][pl]);
    raw[(b * Cout + co0 + c) * HWo + hw] = v;
    float sx = v, sy = v * v;
    #pragma unroll
    for (int o = 32; o; o >>= 1) { sx += __shfl_down(sx, o, 64); sy += __shfl_down(sy, o, 64); }
    if (pl == 0) parts[(co0 + c) * nx + pc] = make_float2(sx, sy);
    if (DOWN) {
      float vd = -(saccD[0][c][pl] + saccD[1][c][pl] + saccD[2][c][pl] + saccD[3][c][pl]);
      rawD[(b * Cout + co0 + c) * HWo + hw] = vd;
      float dx = vd, dy = vd * vd;
      #pragma unroll
      for (int o = 32; o; o >>= 1) { dx += __shfl_down(dx, o, 64); dy += __shfl_down(dy, o, 64); }
      if (pl == 0) partsD[(co0 + c) * nx + pc] = make_float2(dx, dy);
    }
  }
}

// ---------------- conv stem + per-block BN partials (nPart=128)
__global__ void __launch_bounds__(256)
conv_stem_bn(const float* __restrict__ x, const float* __restrict__ w,
             float* __restrict__ raw, float2* __restrict__ partials) {
  const int co = blockIdx.y;
  const int i = blockIdx.x * 256 + threadIdx.x;   // over B*1024
  const int b = i >> 10, hw = i & 1023;
  const int ho = hw >> 5, wo = hw & 31;
  float acc = 0.f;
  #pragma unroll
  for (int ci = 0; ci < 3; ci++) {
    const float* xp = x + (b * 3 + ci) * 1024;
    #pragma unroll
    for (int kh = 0; kh < 3; kh++) {
      int hh = ho + kh - 1;
      bool hv = (hh >= 0) & (hh < 32);
      #pragma unroll
      for (int kw = 0; kw < 3; kw++) {
        int ww = wo + kw - 1;
        float xv = (hv & (ww >= 0) & (ww < 32)) ? xp[hh * 32 + ww] : 0.f;
        acc += xv * w[((co * 3 + ci) * 3 + kh) * 3 + kw];
      }
    }
  }
  raw[(b * 16 + co) * 1024 + hw] = acc;

  float sx = acc, sy = acc * acc;
  #pragma unroll
  for (int o = 32; o; o >>= 1) { sx += __shfl_down(sx, o, 64); sy += __shfl_down(sy, o, 64); }
  __shared__ float2 red[4];
  int lane = threadIdx.x & 63, wid = threadIdx.x >> 6;
  if (lane == 0) red[wid] = make_float2(sx, sy);
  __syncthreads();
  if (threadIdx.x == 0) {
    float2 t = red[0];
    t.x += red[1].x + red[2].x + red[3].x;
    t.y += red[1].y + red[2].y + red[3].y;
    partials[co * 128 + blockIdx.x] = t;
  }
}

// ---------------- final combine + global-avg-pool (HW==64)
__global__ void __launch_bounds__(256)
combine_pool(const float* __restrict__ raw2, const float2* __restrict__ part2, int nPart,
             const float* __restrict__ idsrc, float invN, float* __restrict__ pooled) {
  __shared__ float2 s2[64];
  __shared__ float2 pred[256];
  stats_prologue<64>(part2, nPart, invN, s2, pred);
  int idx = blockIdx.x * 256 + threadIdx.x;
  int c = (idx >> 6) & 63;
  float2 t2 = s2[c];
  float h = fmaxf(fmaf(raw2[idx], t2.x, t2.y) + idsrc[idx], 0.f);
  #pragma unroll
  for (int o = 32; o; o >>= 1) h += __shfl_down(h, o, 64);
  if ((threadIdx.x & 63) == 0) pooled[idx >> 6] = h * (1.f / 64.f);
}

// ---------------- head
__global__ void head_k(const float* __restrict__ pooled, const float* __restrict__ fcw,
                       float* __restrict__ out) {
  __shared__ float logits[320];
  __shared__ float mn[10], rs[10];
  int t = threadIdx.x;
  if (t < 320) {
    int b = t / 10, o = t - b * 10;
    float s = 0.f;
    #pragma unroll
    for (int c = 0; c < 64; c++) s += pooled[b * 64 + c] * fcw[o * 64 + c];
    logits[t] = s;
  }
  __syncthreads();
  if (t < 10) {
    float s = 0.f;
    for (int b = 0; b < 32; b++) s += logits[b * 10 + t];
    float m = s * (1.f / 32.f);
    float v = 0.f;
    for (int b = 0; b < 32; b++) { float d = logits[b * 10 + t] - m; v += d * d; }
    mn[t] = m;
    rs[t] = rsqrtf(v * (1.f / 32.f) + BN_EPS);
  }
  __syncthreads();
  if (t < 320) out[t] = (logits[t] - mn[t % 10]) * rs[t % 10];
}

// ================================================================ host
extern "C" void kernel_launch(void* const* d_in, const int* in_sizes, int n_in,
                              void* d_out, int out_size, void* d_ws, size_t ws_size,
                              hipStream_t stream) {
  const float* x      = (const float*)d_in[0];
  const float* conv1w = (const float*)d_in[1];
  const float* l1w    = (const float*)d_in[2];
  const float* l2w0   = (const float*)d_in[3];
  const float* l2ws   = (const float*)d_in[4];
  const float* l2down = (const float*)d_in[5];
  const float* l3w0   = (const float*)d_in[6];
  const float* l3ws   = (const float*)d_in[7];
  const float* l3down = (const float*)d_in[8];
  const float* fcw    = (const float*)d_in[9];
  float* out = (float*)d_out;

  const int S = 524288;                    // 2 MB in floats
  float* base = (float*)d_ws;
  float* R0  = base + 0 * S;               // stem raw
  float* RA  = base + 1 * S;               // a1 raw (transient)
  float* RB0 = base + 2 * S;               // a2 raw double-buffer
  float* RB1 = base + 3 * S;
  float* HA  = base + 4 * S;               // materialized h double-buffer
  float* HB  = base + 5 * S;
  float* RD  = base + 6 * S;               // downsample raw
  float* pooled = base + 7 * S;            // 2048 floats
  float2* partS  = (float2*)(pooled + 4096);
  float2* partA  = partS  + 8192;
  float2* partB0 = partA  + 8192;
  float2* partB1 = partB0 + 8192;
  float2* partD  = partB1 + 8192;

  const float inv1 = 1.f / 32768.f;        // B*32*32
  const float inv2 = 1.f / 8192.f;         // B*16*16
  const float inv3 = 1.f / 2048.f;         // B*8*8

  const int nx1 = 128;                     // 32768/256
  const int nx2 = 32;                      // 8192/256
  const int nx3 = 32;                      // 2048/64
  const int G1 = nx1 * (16 / 2);           // 1024 blocks
  const int G2 = nx2 * (32 / 2);           // 512 blocks
  const int G3 = nx3 * (64 / 2);           // 1024 blocks

  // 1. stem
  conv_stem_bn<<<dim3(128, 16), 256, 0, stream>>>(x, conv1w, R0, partS);

  // ---- layer1 (16ch @32x32), adder_big CT=2
  // 2. a1 L1b0: input = relu(bn(stem))
  adder_big<16,2,1,false,false><<<G1,256,0,stream>>>(R0, nullptr, partS, 128, nullptr, 0, inv1,
      l1w + 0*2304, nullptr, RA, partA, nullptr, nullptr, nullptr, 16, 32,32,32,32, 1,1, nx1);
  // 3. a2 L1b0
  adder_big<16,2,1,false,false><<<G1,256,0,stream>>>(RA, nullptr, partA, nx1, nullptr, 0, inv1,
      l1w + 1*2304, nullptr, RB0, partB0, nullptr, nullptr, nullptr, 16, 32,32,32,32, 1,1, nx1);
  // 4. a1 L1b1: h0 = relu(bn(RB0) + relu(bn(R0))); writes HA=h0
  adder_big<16,2,4,false,true ><<<G1,256,0,stream>>>(RB0, R0, partB0, nx1, partS, 128, inv1,
      l1w + 2*2304, nullptr, RA, partA, nullptr, nullptr, HA, 16, 32,32,32,32, 1,1, nx1);
  // 5. a2 L1b1
  adder_big<16,2,1,false,false><<<G1,256,0,stream>>>(RA, nullptr, partA, nx1, nullptr, 0, inv1,
      l1w + 3*2304, nullptr, RB1, partB1, nullptr, nullptr, nullptr, 16, 32,32,32,32, 1,1, nx1);
  // 6. a1 L1b2: h1 = relu(bn(RB1) + HA); writes HB=h1
  adder_big<16,2,2,false,true ><<<G1,256,0,stream>>>(RB1, HA, partB1, nx1, nullptr, 0, inv1,
      l1w + 4*2304, nullptr, RA, partA, nullptr, nullptr, HB, 16, 32,32,32,32, 1,1, nx1);
  // 7. a2 L1b2
  adder_big<16,2,1,false,false><<<G1,256,0,stream>>>(RA, nullptr, partA, nx1, nullptr, 0, inv1,
      l1w + 5*2304, nullptr, RB0, partB0, nullptr, nullptr, nullptr, 16, 32,32,32,32, 1,1, nx1);

  // ---- layer2 (32ch @16x16), adder_big CT=2
  // 8. a1 L2b0 (stride2) + fused 1x1 down: h2 = relu(bn(RB0) + HB)
  adder_big<16,2,2,true ,false><<<G2,256,0,stream>>>(RB0, HB, partB0, nx1, nullptr, 0, inv1,
      l2w0, l2down, RA, partA, RD, partD, nullptr, 32, 32,32,16,16, 2,1, nx2);
  // 9. a2 L2b0
  adder_big<32,2,1,false,false><<<G2,256,0,stream>>>(RA, nullptr, partA, nx2, nullptr, 0, inv2,
      l2ws + 0*9216, nullptr, RB1, partB1, nullptr, nullptr, nullptr, 32, 16,16,16,16, 1,1, nx2);
  // 10. a1 L2b1: h = relu(bn(RB1) + bn(RD)); writes HA
  adder_big<32,2,3,false,true ><<<G2,256,0,stream>>>(RB1, RD, partB1, nx2, partD, nx2, inv2,
      l2ws + 1*9216, nullptr, RA, partA, nullptr, nullptr, HA, 32, 16,16,16,16, 1,1, nx2);
  // 11. a2 L2b1
  adder_big<32,2,1,false,false><<<G2,256,0,stream>>>(RA, nullptr, partA, nx2, nullptr, 0, inv2,
      l2ws + 2*9216, nullptr, RB0, partB0, nullptr, nullptr, nullptr, 32, 16,16,16,16, 1,1, nx2);
  // 12. a1 L2b2: h = relu(bn(RB0) + HA); writes HB
  adder_big<32,2,2,false,true ><<<G2,256,0,stream>>>(RB0, HA, partB0, nx2, nullptr, 0, inv2,
      l2ws + 3*9216, nullptr, RA, partA, nullptr, nullptr, HB, 32, 16,16,16,16, 1,1, nx2);
  // 13. a2 L2b2
  adder_big<32,2,1,false,false><<<G2,256,0,stream>>>(RA, nullptr, partA, nx2, nullptr, 0, inv2,
      l2ws + 4*9216, nullptr, RB1, partB1, nullptr, nullptr, nullptr, 32, 16,16,16,16, 1,1, nx2);

  // ---- layer3 (64ch @8x8), adder_small CT=2
  // 14. a1 L3b0 (stride2) + fused down: h = relu(bn(RB1) + HB)
  adder_small<32,2,2,true ,false><<<G3,256,0,stream>>>(RB1, HB, partB1, nx2, nullptr, 0, inv2,
      l3w0, l3down, RA, partA, RD, partD, nullptr, 64, 16,16,8,8, 2,1, nx3);
  // 15. a2 L3b0
  adder_small<64,2,1,false,false><<<G3,256,0,stream>>>(RA, nullptr, partA, nx3, nullptr, 0, inv3,
      l3ws + 0*36864, nullptr, RB0, partB0, nullptr, nullptr, nullptr, 64, 8,8,8,8, 1,1, nx3);
  // 16. a1 L3b1: h = relu(bn(RB0) + bn(RD)); writes HA
  adder_small<64,2,3,false,true ><<<G3,256,0,stream>>>(RB0, RD, partB0, nx3, partD, nx3, inv3,
      l3ws + 1*36864, nullptr, RA, partA, nullptr, nullptr, HA, 64, 8,8,8,8, 1,1, nx3);
  // 17. a2 L3b1
  adder_small<64,2,1,false,false><<<G3,256,0,stream>>>(RA, nullptr, partA, nx3, nullptr, 0, inv3,
      l3ws + 2*36864, nullptr, RB1, partB1, nullptr, nullptr, nullptr, 64, 8,8,8,8, 1,1, nx3);
  // 18. a1 L3b2: h = relu(bn(RB1) + HA); writes HB
  adder_small<64,2,2,false,true ><<<G3,256,0,stream>>>(RB1, HA, partB1, nx3, nullptr, 0, inv3,
      l3ws + 3*36864, nullptr, RA, partA, nullptr, nullptr, HB, 64, 8,8,8,8, 1,1, nx3);
  // 19. a2 L3b2
  adder_small<64,2,1,false,false><<<G3,256,0,stream>>>(RA, nullptr, partA, nx3, nullptr, 0, inv3,
      l3ws + 4*36864, nullptr, RB0, partB0, nullptr, nullptr, nullptr, 64, 8,8,8,8, 1,1, nx3);

  // 20. final combine + pool: h = relu(bn(RB0) + HB) -> pooled
  combine_pool<<<512, 256, 0, stream>>>(RB0, partB0, nx3, HB, inv3, pooled);

  // 21. head
  head_k<<<1, 320, 0, stream>>>(pooled, fcw, out);
}

// Round 10
// 616.791 us; speedup vs baseline: 5.5084x; 1.1072x over previous
//
#include <hip/hip_runtime.h>

#define BN_EPS 1e-5f

// All activations are NHWC: elem(b,h,w,c) at [((b*H+h)*W+w)*C + c], C∈{16,32,64}.
// Weights stay as given: [Cout][Cin][3][3].

// ---------------- stats prologue: [C][nPart] (sum,sumsq) -> smr[c]=(rstd, -mean*rstd)
template<int C>
__device__ __forceinline__ void stats_prologue(const float2* __restrict__ part,
                                               int nPart, float invN,
                                               float2* smr, float2* pred) {
  const int TPC = 256 / C;
  int c  = threadIdx.x / TPC;
  int sl = threadIdx.x - c * TPC;
  float s = 0.f, s2 = 0.f;
  for (int j = sl; j < nPart; j += TPC) {
    float2 p = part[c * nPart + j];
    s += p.x; s2 += p.y;
  }
  pred[threadIdx.x] = make_float2(s, s2);
  __syncthreads();
  for (int st = TPC >> 1; st; st >>= 1) {
    if (sl < st) {
      pred[threadIdx.x].x += pred[threadIdx.x + st].x;
      pred[threadIdx.x].y += pred[threadIdx.x + st].y;
    }
    __syncthreads();
  }
  if (sl == 0) {
    float m   = pred[threadIdx.x].x * invN;
    float var = fmaxf(pred[threadIdx.x].y * invN - m * m, 0.f);
    float r   = rsqrtf(var + BN_EPS);
    smr[c] = make_float2(r, -m * r);
  }
  __syncthreads();
}

// Virtual-input transform (applied ONLY to in-bounds taps; OOB taps stay 0 —
// activation precedes patch extraction, so zero-padding contributes |0-w|):
//  0: a; 1: relu(bnA(a)); 2: relu(bnA(a)+b); 3: relu(bnA(a)+bnB(b));
//  4: relu(bnA(a)+relu(bnB(b)))
template<int INM>
__device__ __forceinline__ float xf(float a, float b, float2 tA, float2 tB) {
  if (INM == 0) return a;
  if (INM == 1) return fmaxf(fmaf(a, tA.x, tA.y), 0.f);
  if (INM == 2) return fmaxf(fmaf(a, tA.x, tA.y) + b, 0.f);
  if (INM == 3) return fmaxf(fmaf(a, tA.x, tA.y) + fmaf(b, tB.x, tB.y), 0.f);
  /* 4 */        return fmaxf(fmaf(a, tA.x, tA.y) + fmaxf(fmaf(b, tB.x, tB.y), 0.f), 0.f);
}

// ---------------- big adder (L1/L2): 256 positions/block, full Cin/thread in
// float4 chunks, CT=2 out-channels/thread. 1D XCD-swizzled grid (nx * Cout/2).
// Emits per-(block,channel) BN partials. DOWN: fused 1x1 stride-2 adder via
// center tap. HWRITE (stride-1, cog==0): writes transformed h to hout (NHWC).
template<int CIN, int INM, bool DOWN, bool HWRITE>
__global__ void __launch_bounds__(256, 4)
adder_big(const float* __restrict__ A, const float* __restrict__ Bt,
          const float2* __restrict__ pA, int nPA,
          const float2* __restrict__ pB, int nPB, float invNin,
          const float* __restrict__ w, const float* __restrict__ wD,
          float* __restrict__ raw, float2* __restrict__ parts,
          float* __restrict__ rawD, float2* __restrict__ partsD,
          float* __restrict__ hout,
          int Cout, int H, int W, int Ho, int Wo, int stride, int pad, int nx) {
  __shared__ float2 pred[256];
  __shared__ float2 smA[(INM >= 1) ? CIN : 1];
  __shared__ float2 smB[(INM >= 3) ? CIN : 1];
  __shared__ float2 bred[4][2];
  __shared__ float2 bredD[DOWN ? 4 : 1][DOWN ? 2 : 1];
  if (INM >= 1) stats_prologue<CIN>(pA, nPA, invNin, smA, pred);
  if (INM >= 3) stats_prologue<CIN>(pB, nPB, invNin, smB, pred);

  const int id = blockIdx.x, span = nx >> 3;
  const int xcd = id & 7, slot = id >> 3;
  const int pc  = xcd * span + slot % span;
  const int cog = slot / span, co0 = cog * 2;

  const int HWo = Ho * Wo;
  const int i  = pc * 256 + threadIdx.x;      // output position (b-major)
  const int b  = i / HWo, hw = i - b * HWo;
  const int ho = hw / Wo, wo = hw - ho * Wo;

  int off[9]; bool val[9];
  #pragma unroll
  for (int kh = 0; kh < 3; kh++) {
    int hh = ho * stride + kh - pad;
    bool hv = (hh >= 0) & (hh < H);
    #pragma unroll
    for (int kw = 0; kw < 3; kw++) {
      int ww = wo * stride + kw - pad;
      val[kh * 3 + kw] = hv & (ww >= 0) & (ww < W);
      off[kh * 3 + kw] = (b * H + hh) * W + ww;   // input position index
    }
  }

  float acc0 = 0.f, acc1 = 0.f;
  float accD0 = 0.f, accD1 = 0.f;

  #pragma unroll 1
  for (int cb = 0; cb < CIN; cb += 4) {
    float2 tA0, tA1, tA2, tA3, tB0, tB1, tB2, tB3;
    if (INM >= 1) { tA0 = smA[cb]; tA1 = smA[cb+1]; tA2 = smA[cb+2]; tA3 = smA[cb+3]; }
    if (INM >= 3) { tB0 = smB[cb]; tB1 = smB[cb+1]; tB2 = smB[cb+2]; tB3 = smB[cb+3]; }
    float4 q[9];
    #pragma unroll
    for (int t = 0; t < 9; t++) {
      float4 a4 = make_float4(0.f, 0.f, 0.f, 0.f);
      if (val[t]) {
        a4 = *reinterpret_cast<const float4*>(A + (size_t)off[t] * CIN + cb);
        if (INM >= 1) {
          float4 b4 = make_float4(0.f, 0.f, 0.f, 0.f);
          if (INM >= 2) b4 = *reinterpret_cast<const float4*>(Bt + (size_t)off[t] * CIN + cb);
          a4.x = xf<INM>(a4.x, b4.x, tA0, tB0);
          a4.y = xf<INM>(a4.y, b4.y, tA1, tB1);
          a4.z = xf<INM>(a4.z, b4.z, tA2, tB2);
          a4.w = xf<INM>(a4.w, b4.w, tA3, tB3);
        }
      }
      q[t] = a4;
    }
    if (HWRITE) {
      if (cog == 0) *reinterpret_cast<float4*>(hout + (size_t)i * CIN + cb) = q[4];
    }
    #pragma unroll
    for (int c = 0; c < 2; c++) {
      const float* wp = w + ((co0 + c) * CIN + cb) * 9;   // wave-uniform -> s_load
      float a = 0.f;
      #pragma unroll
      for (int t = 0; t < 9; t++) {
        a += fabsf(q[t].x - wp[t]) + fabsf(q[t].y - wp[9 + t])
           + fabsf(q[t].z - wp[18 + t]) + fabsf(q[t].w - wp[27 + t]);
      }
      if (c == 0) acc0 += a; else acc1 += a;
      if (DOWN) {
        const float* wdp = wD + (co0 + c) * CIN + cb;
        float d = fabsf(q[4].x - wdp[0]) + fabsf(q[4].y - wdp[1])
                + fabsf(q[4].z - wdp[2]) + fabsf(q[4].w - wdp[3]);
        if (c == 0) accD0 += d; else accD1 += d;
      }
    }
  }

  const int lane = threadIdx.x & 63, wid = threadIdx.x >> 6;
  float v0 = -acc0, v1 = -acc1;
  *reinterpret_cast<float2*>(raw + (size_t)i * Cout + co0) = make_float2(v0, v1);
  {
    float sx = v0, sy = v0 * v0, ux = v1, uy = v1 * v1;
    #pragma unroll
    for (int o = 32; o; o >>= 1) {
      sx += __shfl_down(sx, o, 64); sy += __shfl_down(sy, o, 64);
      ux += __shfl_down(ux, o, 64); uy += __shfl_down(uy, o, 64);
    }
    if (lane == 0) { bred[wid][0] = make_float2(sx, sy); bred[wid][1] = make_float2(ux, uy); }
  }
  if (DOWN) {
    float d0 = -accD0, d1 = -accD1;
    *reinterpret_cast<float2*>(rawD + (size_t)i * Cout + co0) = make_float2(d0, d1);
    float sx = d0, sy = d0 * d0, ux = d1, uy = d1 * d1;
    #pragma unroll
    for (int o = 32; o; o >>= 1) {
      sx += __shfl_down(sx, o, 64); sy += __shfl_down(sy, o, 64);
      ux += __shfl_down(ux, o, 64); uy += __shfl_down(uy, o, 64);
    }
    if (lane == 0) { bredD[wid][0] = make_float2(sx, sy); bredD[wid][1] = make_float2(ux, uy); }
  }
  __syncthreads();
  if (threadIdx.x < 2) {
    const int c = threadIdx.x;
    float2 t = bred[0][c];
    #pragma unroll
    for (int wv = 1; wv < 4; wv++) { t.x += bred[wv][c].x; t.y += bred[wv][c].y; }
    parts[(co0 + c) * nx + pc] = t;
    if (DOWN) {
      float2 td = bredD[0][c];
      #pragma unroll
      for (int wv = 1; wv < 4; wv++) { td.x += bredD[wv][c].x; td.y += bredD[wv][c].y; }
      partsD[(co0 + c) * nx + pc] = td;
    }
  }
}

// ---------------- layer3 split-K stage1: grid (8, 16, CINF/ZCI).
// 256 positions/block, CT=4 co, ZCI input channels (this z-slice) in float4
// chunks. Writes POSITIVE partial planes pout[z][pos][co] (NHWC, coalesced).
// HWRITE: cog==0 writes its transformed ci-slice of h to hout.
template<int CINF, int ZCI, int INM, bool DOWN, bool HWRITE>
__global__ void __launch_bounds__(256, 4)
adder_s1(const float* __restrict__ A, const float* __restrict__ Bt,
         const float2* __restrict__ pA, int nPA,
         const float2* __restrict__ pB, int nPB, float invNin,
         const float* __restrict__ w, const float* __restrict__ wD,
         float* __restrict__ pout, float* __restrict__ poutD,
         float* __restrict__ hout,
         int H, int W, int stride, int pad) {
  __shared__ float2 pred[256];
  __shared__ float2 smA[(INM >= 1) ? CINF : 1];
  __shared__ float2 smB[(INM >= 3) ? CINF : 1];
  if (INM >= 1) stats_prologue<CINF>(pA, nPA, invNin, smA, pred);
  if (INM >= 3) stats_prologue<CINF>(pB, nPB, invNin, smB, pred);

  const int i  = blockIdx.x * 256 + threadIdx.x;  // output position in [0,2048)
  const int b  = i >> 6, hw = i & 63;
  const int ho = hw >> 3, wo = hw & 7;
  const int co0 = blockIdx.y * 4;
  const int z   = blockIdx.z, ci0z = z * ZCI;

  int off[9]; bool val[9];
  #pragma unroll
  for (int kh = 0; kh < 3; kh++) {
    int hh = ho * stride + kh - pad;
    bool hv = (hh >= 0) & (hh < H);
    #pragma unroll
    for (int kw = 0; kw < 3; kw++) {
      int ww = wo * stride + kw - pad;
      val[kh * 3 + kw] = hv & (ww >= 0) & (ww < W);
      off[kh * 3 + kw] = (b * H + hh) * W + ww;
    }
  }

  float acc[4] = {0.f, 0.f, 0.f, 0.f};
  float accD[4] = {0.f, 0.f, 0.f, 0.f};

  #pragma unroll 1
  for (int u = 0; u < ZCI; u += 4) {
    const int cb = ci0z + u;
    float2 tA0, tA1, tA2, tA3, tB0, tB1, tB2, tB3;
    if (INM >= 1) { tA0 = smA[cb]; tA1 = smA[cb+1]; tA2 = smA[cb+2]; tA3 = smA[cb+3]; }
    if (INM >= 3) { tB0 = smB[cb]; tB1 = smB[cb+1]; tB2 = smB[cb+2]; tB3 = smB[cb+3]; }
    float4 q[9];
    #pragma unroll
    for (int t = 0; t < 9; t++) {
      float4 a4 = make_float4(0.f, 0.f, 0.f, 0.f);
      if (val[t]) {
        a4 = *reinterpret_cast<const float4*>(A + (size_t)off[t] * CINF + cb);
        if (INM >= 1) {
          float4 b4 = make_float4(0.f, 0.f, 0.f, 0.f);
          if (INM >= 2) b4 = *reinterpret_cast<const float4*>(Bt + (size_t)off[t] * CINF + cb);
          a4.x = xf<INM>(a4.x, b4.x, tA0, tB0);
          a4.y = xf<INM>(a4.y, b4.y, tA1, tB1);
          a4.z = xf<INM>(a4.z, b4.z, tA2, tB2);
          a4.w = xf<INM>(a4.w, b4.w, tA3, tB3);
        }
      }
      q[t] = a4;
    }
    if (HWRITE) {
      if (blockIdx.y == 0) *reinterpret_cast<float4*>(hout + (size_t)i * CINF + cb) = q[4];
    }
    #pragma unroll
    for (int c = 0; c < 4; c++) {
      const float* wp = w + ((co0 + c) * CINF + cb) * 9;
      float a = 0.f;
      #pragma unroll
      for (int t = 0; t < 9; t++) {
        a += fabsf(q[t].x - wp[t]) + fabsf(q[t].y - wp[9 + t])
           + fabsf(q[t].z - wp[18 + t]) + fabsf(q[t].w - wp[27 + t]);
      }
      acc[c] += a;
      if (DOWN) {
        const float* wdp = wD + (co0 + c) * CINF + cb;
        accD[c] += fabsf(q[4].x - wdp[0]) + fabsf(q[4].y - wdp[1])
                 + fabsf(q[4].z - wdp[2]) + fabsf(q[4].w - wdp[3]);
      }
    }
  }

  const size_t pbase = (size_t)z * 131072 + (size_t)i * 64 + co0;
  *reinterpret_cast<float4*>(pout + pbase) = make_float4(acc[0], acc[1], acc[2], acc[3]);
  if (DOWN)
    *reinterpret_cast<float4*>(poutD + pbase) = make_float4(accD[0], accD[1], accD[2], accD[3]);
}

// ---------------- layer3 stage2 reduce: raw = -sum_z planes; BN partials.
// grid 128, block 256; each thread 4 elems (stride 256). channel = t&63.
template<int NC, bool DUAL>
__global__ void __launch_bounds__(256)
reduce_l3(const float* __restrict__ pin, float* __restrict__ raw, float2* __restrict__ parts,
          const float* __restrict__ pinD, float* __restrict__ rawD, float2* __restrict__ partsD) {
  __shared__ float2 sums[256];
  const int base = blockIdx.x * 1024 + threadIdx.x;
  float sx = 0.f, sy = 0.f, dx = 0.f, dy = 0.f;
  #pragma unroll
  for (int k = 0; k < 4; k++) {
    int idx = base + k * 256;
    float s = 0.f;
    #pragma unroll
    for (int zz = 0; zz < NC; zz++) s += pin[zz * 131072 + idx];
    float v = -s;
    raw[idx] = v;
    sx += v; sy += v * v;
    if (DUAL) {
      float sd = 0.f;
      #pragma unroll
      for (int zz = 0; zz < NC; zz++) sd += pinD[zz * 131072 + idx];
      float vd = -sd;
      rawD[idx] = vd;
      dx += vd; dy += vd * vd;
    }
  }
  sums[threadIdx.x] = make_float2(sx, sy);
  __syncthreads();
  if (threadIdx.x < 64) {
    float2 t = sums[threadIdx.x];
    t.x += sums[threadIdx.x + 64].x + sums[threadIdx.x + 128].x + sums[threadIdx.x + 192].x;
    t.y += sums[threadIdx.x + 64].y + sums[threadIdx.x + 128].y + sums[threadIdx.x + 192].y;
    parts[threadIdx.x * 128 + blockIdx.x] = t;
  }
  if (DUAL) {
    __syncthreads();
    sums[threadIdx.x] = make_float2(dx, dy);
    __syncthreads();
    if (threadIdx.x < 64) {
      float2 t = sums[threadIdx.x];
      t.x += sums[threadIdx.x + 64].x + sums[threadIdx.x + 128].x + sums[threadIdx.x + 192].x;
      t.y += sums[threadIdx.x + 64].y + sums[threadIdx.x + 128].y + sums[threadIdx.x + 192].y;
      partsD[threadIdx.x * 128 + blockIdx.x] = t;
    }
  }
}

// ---------------- conv stem (NCHW in) -> NHWC raw + per-block BN partials
__global__ void __launch_bounds__(256)
conv_stem_bn(const float* __restrict__ x, const float* __restrict__ w,
             float* __restrict__ raw, float2* __restrict__ partials) {
  const int i = blockIdx.x * 256 + threadIdx.x;   // position, b-major (32768)
  const int b = i >> 10, hw = i & 1023;
  const int ho = hw >> 5, wo = hw & 31;
  float xv[27];
  #pragma unroll
  for (int ci = 0; ci < 3; ci++) {
    const float* xp = x + (b * 3 + ci) * 1024;
    #pragma unroll
    for (int kh = 0; kh < 3; kh++) {
      int hh = ho + kh - 1;
      bool hv = (hh >= 0) & (hh < 32);
      #pragma unroll
      for (int kw = 0; kw < 3; kw++) {
        int ww = wo + kw - 1;
        xv[(ci * 3 + kh) * 3 + kw] = (hv & (ww >= 0) & (ww < 32)) ? xp[hh * 32 + ww] : 0.f;
      }
    }
  }
  float acc[16];
  #pragma unroll
  for (int co = 0; co < 16; co++) {
    float a = 0.f;
    const float* wp = w + co * 27;
    #pragma unroll
    for (int t = 0; t < 27; t++) a += xv[t] * wp[t];
    acc[co] = a;
  }
  #pragma unroll
  for (int cb = 0; cb < 16; cb += 4)
    *reinterpret_cast<float4*>(raw + (size_t)i * 16 + cb) =
        make_float4(acc[cb], acc[cb+1], acc[cb+2], acc[cb+3]);

  __shared__ float2 red[4][16];
  const int lane = threadIdx.x & 63, wid = threadIdx.x >> 6;
  #pragma unroll
  for (int co = 0; co < 16; co++) {
    float sx = acc[co], sy = acc[co] * acc[co];
    #pragma unroll
    for (int o = 32; o; o >>= 1) { sx += __shfl_down(sx, o, 64); sy += __shfl_down(sy, o, 64); }
    if (lane == 0) red[wid][co] = make_float2(sx, sy);
  }
  __syncthreads();
  if (threadIdx.x < 16) {
    float2 t = red[0][threadIdx.x];
    #pragma unroll
    for (int wv = 1; wv < 4; wv++) { t.x += red[wv][threadIdx.x].x; t.y += red[wv][threadIdx.x].y; }
    partials[threadIdx.x * 128 + blockIdx.x] = t;
  }
}

// ---------------- final combine + per-image pool: grid 32 (block = image b)
__global__ void __launch_bounds__(256)
pool_combine(const float* __restrict__ raw2, const float2* __restrict__ part2,
             const float* __restrict__ idsrc, float invN, float* __restrict__ pooled) {
  __shared__ float2 s2[64];
  __shared__ float2 pred[256];
  __shared__ float sums[256];
  stats_prologue<64>(part2, 128, invN, s2, pred);
  const int b = blockIdx.x, c = threadIdx.x & 63, pr = threadIdx.x >> 6;
  float2 t2 = s2[c];
  float s = 0.f;
  #pragma unroll
  for (int k = 0; k < 16; k++) {
    int pos = k * 4 + pr;
    int idx = b * 4096 + pos * 64 + c;
    s += fmaxf(fmaf(raw2[idx], t2.x, t2.y) + idsrc[idx], 0.f);
  }
  sums[threadIdx.x] = s;
  __syncthreads();
  if (threadIdx.x < 64) {
    float t = sums[threadIdx.x] + sums[threadIdx.x + 64] + sums[threadIdx.x + 128] + sums[threadIdx.x + 192];
    pooled[b * 64 + threadIdx.x] = t * (1.f / 64.f);
  }
}

// ---------------- head
__global__ void head_k(const float* __restrict__ pooled, const float* __restrict__ fcw,
                       float* __restrict__ out) {
  __shared__ float logits[320];
  __shared__ float mn[10], rs[10];
  int t = threadIdx.x;
  if (t < 320) {
    int b = t / 10, o = t - b * 10;
    float s = 0.f;
    #pragma unroll
    for (int c = 0; c < 64; c++) s += pooled[b * 64 + c] * fcw[o * 64 + c];
    logits[t] = s;
  }
  __syncthreads();
  if (t < 10) {
    float s = 0.f;
    for (int b = 0; b < 32; b++) s += logits[b * 10 + t];
    float m = s * (1.f / 32.f);
    float v = 0.f;
    for (int b = 0; b < 32; b++) { float d = logits[b * 10 + t] - m; v += d * d; }
    mn[t] = m;
    rs[t] = rsqrtf(v * (1.f / 32.f) + BN_EPS);
  }
  __syncthreads();
  if (t < 320) out[t] = (logits[t] - mn[t % 10]) * rs[t % 10];
}

// ================================================================ host
extern "C" void kernel_launch(void* const* d_in, const int* in_sizes, int n_in,
                              void* d_out, int out_size, void* d_ws, size_t ws_size,
                              hipStream_t stream) {
  const float* x      = (const float*)d_in[0];
  const float* conv1w = (const float*)d_in[1];
  const float* l1w    = (const float*)d_in[2];
  const float* l2w0   = (const float*)d_in[3];
  const float* l2ws   = (const float*)d_in[4];
  const float* l2down = (const float*)d_in[5];
  const float* l3w0   = (const float*)d_in[6];
  const float* l3ws   = (const float*)d_in[7];
  const float* l3down = (const float*)d_in[8];
  const float* fcw    = (const float*)d_in[9];
  float* out = (float*)d_out;

  const int S = 524288;                    // 2 MB in floats
  float* base = (float*)d_ws;
  float* R0  = base + 0 * S;               // stem raw  [32768][16]
  float* RA  = base + 1 * S;               // a1 raw
  float* RB0 = base + 2 * S;               // a2 raw dbuf
  float* RB1 = base + 3 * S;
  float* HA  = base + 4 * S;               // h dbuf
  float* HB  = base + 5 * S;
  float* RD  = base + 6 * S;               // down raw
  float* PA  = base + 7 * S;               // L3 planes main: 8 x 131072 (4 MB)
  float* PD  = base + 9 * S;               // L3 planes down: 4 x 131072 (2 MB)
  float* pooled = base + 10 * S;           // 2048
  float2* partS  = (float2*)(pooled + 4096);  // [16][128]
  float2* partA  = partS  + 8192;             // [64][128] max
  float2* partB0 = partA  + 8192;
  float2* partB1 = partB0 + 8192;
  float2* partD  = partB1 + 8192;

  const float inv1 = 1.f / 32768.f, inv2 = 1.f / 8192.f, inv3 = 1.f / 2048.f;
  const int nx1 = 128, nx2 = 32;
  const int G1 = nx1 * 8;                  // 1024 blocks (16ch / CT2)
  const int G2 = nx2 * 16;                 // 512 blocks (32ch / CT2)

  // 1. stem
  conv_stem_bn<<<128, 256, 0, stream>>>(x, conv1w, R0, partS);

  // ---- layer1 (16ch @32x32)
  adder_big<16,1,false,false><<<G1,256,0,stream>>>(R0, nullptr, partS, 128, nullptr, 0, inv1,
      l1w + 0*2304, nullptr, RA, partA, nullptr, nullptr, nullptr, 16, 32,32,32,32, 1,1, nx1);
  adder_big<16,1,false,false><<<G1,256,0,stream>>>(RA, nullptr, partA, nx1, nullptr, 0, inv1,
      l1w + 1*2304, nullptr, RB0, partB0, nullptr, nullptr, nullptr, 16, 32,32,32,32, 1,1, nx1);
  adder_big<16,4,false,true ><<<G1,256,0,stream>>>(RB0, R0, partB0, nx1, partS, 128, inv1,
      l1w + 2*2304, nullptr, RA, partA, nullptr, nullptr, HA, 16, 32,32,32,32, 1,1, nx1);
  adder_big<16,1,false,false><<<G1,256,0,stream>>>(RA, nullptr, partA, nx1, nullptr, 0, inv1,
      l1w + 3*2304, nullptr, RB1, partB1, nullptr, nullptr, nullptr, 16, 32,32,32,32, 1,1, nx1);
  adder_big<16,2,false,true ><<<G1,256,0,stream>>>(RB1, HA, partB1, nx1, nullptr, 0, inv1,
      l1w + 4*2304, nullptr, RA, partA, nullptr, nullptr, HB, 16, 32,32,32,32, 1,1, nx1);
  adder_big<16,1,false,false><<<G1,256,0,stream>>>(RA, nullptr, partA, nx1, nullptr, 0, inv1,
      l1w + 5*2304, nullptr, RB0, partB0, nullptr, nullptr, nullptr, 16, 32,32,32,32, 1,1, nx1);

  // ---- layer2 (32ch @16x16)
  adder_big<16,2,true ,false><<<G2,256,0,stream>>>(RB0, HB, partB0, nx1, nullptr, 0, inv1,
      l2w0, l2down, RA, partA, RD, partD, nullptr, 32, 32,32,16,16, 2,1, nx2);
  adder_big<32,1,false,false><<<G2,256,0,stream>>>(RA, nullptr, partA, nx2, nullptr, 0, inv2,
      l2ws + 0*9216, nullptr, RB1, partB1, nullptr, nullptr, nullptr, 32, 16,16,16,16, 1,1, nx2);
  adder_big<32,3,false,true ><<<G2,256,0,stream>>>(RB1, RD, partB1, nx2, partD, nx2, inv2,
      l2ws + 1*9216, nullptr, RA, partA, nullptr, nullptr, HA, 32, 16,16,16,16, 1,1, nx2);
  adder_big<32,1,false,false><<<G2,256,0,stream>>>(RA, nullptr, partA, nx2, nullptr, 0, inv2,
      l2ws + 2*9216, nullptr, RB0, partB0, nullptr, nullptr, nullptr, 32, 16,16,16,16, 1,1, nx2);
  adder_big<32,2,false,true ><<<G2,256,0,stream>>>(RB0, HA, partB0, nx2, nullptr, 0, inv2,
      l2ws + 3*9216, nullptr, RA, partA, nullptr, nullptr, HB, 32, 16,16,16,16, 1,1, nx2);
  adder_big<32,1,false,false><<<G2,256,0,stream>>>(RA, nullptr, partA, nx2, nullptr, 0, inv2,
      l2ws + 4*9216, nullptr, RB1, partB1, nullptr, nullptr, nullptr, 32, 16,16,16,16, 1,1, nx2);

  // ---- layer3 (64ch @8x8): split-K planes + reduce
  // b0: a1 (stride2, Cin=32, z=4) + fused down
  adder_s1<32,8,2,true ,false><<<dim3(8,16,4),256,0,stream>>>(RB1, HB, partB1, nx2, nullptr, 0, inv2,
      l3w0, l3down, PA, PD, nullptr, 16,16, 2,1);
  reduce_l3<4,true ><<<128,256,0,stream>>>(PA, RA, partA, PD, RD, partD);
  adder_s1<64,8,1,false,false><<<dim3(8,16,8),256,0,stream>>>(RA, nullptr, partA, 128, nullptr, 0, inv3,
      l3ws + 0*36864, nullptr, PA, nullptr, nullptr, 8,8, 1,1);
  reduce_l3<8,false><<<128,256,0,stream>>>(PA, RB0, partB0, nullptr, nullptr, nullptr);
  // b1
  adder_s1<64,8,3,false,true ><<<dim3(8,16,8),256,0,stream>>>(RB0, RD, partB0, 128, partD, 128, inv3,
      l3ws + 1*36864, nullptr, PA, nullptr, HA, 8,8, 1,1);
  reduce_l3<8,false><<<128,256,0,stream>>>(PA, RA, partA, nullptr, nullptr, nullptr);
  adder_s1<64,8,1,false,false><<<dim3(8,16,8),256,0,stream>>>(RA, nullptr, partA, 128, nullptr, 0, inv3,
      l3ws + 2*36864, nullptr, PA, nullptr, nullptr, 8,8, 1,1);
  reduce_l3<8,false><<<128,256,0,stream>>>(PA, RB1, partB1, nullptr, nullptr, nullptr);
  // b2
  adder_s1<64,8,2,false,true ><<<dim3(8,16,8),256,0,stream>>>(RB1, HA, partB1, 128, nullptr, 0, inv3,
      l3ws + 3*36864, nullptr, PA, nullptr, HB, 8,8, 1,1);
  reduce_l3<8,false><<<128,256,0,stream>>>(PA, RA, partA, nullptr, nullptr, nullptr);
  adder_s1<64,8,1,false,false><<<dim3(8,16,8),256,0,stream>>>(RA, nullptr, partA, 128, nullptr, 0, inv3,
      l3ws + 4*36864, nullptr, PA, nullptr, nullptr, 8,8, 1,1);
  reduce_l3<8,false><<<128,256,0,stream>>>(PA, RB0, partB0, nullptr, nullptr, nullptr);

  // final combine + pool, then head
  pool_combine<<<32, 256, 0, stream>>>(RB0, partB0, HB, inv3, pooled);
  head_k<<<1, 320, 0, stream>>>(pooled, fcw, out);
}